// Round 16
// baseline (249.051 us; speedup 1.0000x reference)
//
#include <hip/hip_runtime.h>
#include <hip/hip_bf16.h>

using bf16 = __hip_bfloat16;
typedef __attribute__((ext_vector_type(8))) short bf16x8;
typedef __attribute__((ext_vector_type(4))) float f32x4;
typedef __attribute__((ext_vector_type(4))) int i32x4;

#define DECAY 0.25f

// ---------------------------------------------------------------- helpers
__device__ __forceinline__ void gload_lds16(const void* g, void* l) {
  __builtin_amdgcn_global_load_lds(
      (const __attribute__((address_space(1))) void*)g,
      (__attribute__((address_space(3))) void*)l, 16, 0, 0);
}

__device__ __forceinline__ unsigned short f2bf(float f) {
  __hip_bfloat16 h = __float2bfloat16(f);
  return *reinterpret_cast<unsigned short*>(&h);
}

// ---------------------------------------------------------------- prep kernels
__global__ void transpose_cast_k(const float* __restrict__ w, bf16* __restrict__ wt, int N) {
  __shared__ float t[32][33];
  int bx = blockIdx.x * 32, by = blockIdx.y * 32;
  int tx = threadIdx.x, ty = threadIdx.y;  // block (32,8)
#pragma unroll
  for (int i = 0; i < 32; i += 8)
    t[ty + i][tx] = w[(size_t)(by + ty + i) * N + bx + tx];
  __syncthreads();
#pragma unroll
  for (int i = 0; i < 32; i += 8)
    wt[(size_t)(bx + ty + i) * N + by + tx] = __float2bfloat16(t[tx][ty + i]);
}

__global__ void colmax_part_k(const float* __restrict__ w, unsigned int* __restrict__ maxbits,
                              int N, int KCH) {
  int n = blockIdx.x * blockDim.x + threadIdx.x;
  int k0 = blockIdx.y * KCH;
  float mx = 0.f;
  for (int k = k0; k < k0 + KCH; ++k) mx = fmaxf(mx, fabsf(w[(size_t)k * N + n]));
  atomicMax(&maxbits[n], __float_as_uint(mx));
}

__global__ void transpose_quant_k(const float* __restrict__ w,
                                  const unsigned int* __restrict__ maxbits,
                                  signed char* __restrict__ wq, int N, int K) {
  __shared__ float t[32][33];
  int bx = blockIdx.x * 32, by = blockIdx.y * 32;  // bx: n-range, by: k-range
  int tx = threadIdx.x, ty = threadIdx.y;          // block (32,8)
#pragma unroll
  for (int i = 0; i < 32; i += 8)
    t[ty + i][tx] = w[(size_t)(by + ty + i) * N + bx + tx];
  __syncthreads();
#pragma unroll
  for (int i = 0; i < 32; i += 8) {
    int n = bx + ty + i;
    float mx = __uint_as_float(maxbits[n]);
    float inv = (mx > 0.f) ? 127.f / mx : 0.f;
    int q = __float2int_rn(t[tx][ty + i] * inv);
    q = max(-127, min(127, q));
    wq[(size_t)n * K + by + tx] = (signed char)q;
  }
}

// ---------------------------------------------------------------- staging: ROW-MAJOR + XOR pre-swizzled source (R14, verified)
// 128B-row region [256][128B]: byte row*128 + c16*16 holds
// src[row0+row][k0 + (c16^(row&7))*8 bf16]. LINEAR LDS dest, permuted global src.
__device__ __forceinline__ void stage_row_bf16(const bf16* __restrict__ src, int ldk,
                                               int row0, int k0, char* region, int tid) {
#pragma unroll
  for (int u = 0; u < 4; ++u) {
    int d = tid * 16 + u * 8192;
    int row = d >> 7;
    int sc = ((d >> 4) & 7) ^ (row & 7);
    const bf16* g = src + (size_t)(row0 + row) * ldk + k0 + sc * 8;
    gload_lds16(g, region + d);
  }
}

// swizzled read address for 128B-row regions
__device__ __forceinline__ const char* swz(const char* region, int r, int c16) {
  return region + r * 128 + (((c16 ^ (r & 7)) & 7) << 4);
}

// 64B-row i8 regions (BK=64): byte row*64 + c*16 holds src[row0+row][k0+(c^(row&3))*16]
__device__ __forceinline__ void stageA_i8_64(const signed char* __restrict__ src, int ldk,
                                             int row0, int k0, char* region, int tid) {
  int d = tid * 16;  // 8KB: 128 rows
  int row = d >> 6;
  int sc = ((d >> 4) & 3) ^ (row & 3);
  const signed char* g = src + (size_t)(row0 + row) * ldk + k0 + sc * 16;
  gload_lds16(g, region + d);
}

__device__ __forceinline__ void stageB_i8_64(const signed char* __restrict__ src, int ldk,
                                             int row0, int k0, char* region, int tid) {
#pragma unroll
  for (int u = 0; u < 2; ++u) {
    int d = tid * 16 + u * 8192;  // 16KB: 256 rows
    int row = d >> 6;
    int sc = ((d >> 4) & 3) ^ (row & 3);
    const signed char* g = src + (size_t)(row0 + row) * ldk + k0 + sc * 16;
    gload_lds16(g, region + d);
  }
}

__device__ __forceinline__ const char* swz64(const char* region, int r, int c) {
  return region + r * 64 + ((((c) ^ (r & 3)) & 3) << 4);
}

// ---------------------------------------------------------------- A reg-stage from f32 x (fused cast; R15, verified)
__device__ __forceinline__ void stageA_load_f32(const float* __restrict__ X, int ldk,
                                                int row0, int k0, int tid,
                                                f32x4 (&v)[4][2]) {
#pragma unroll
  for (int u = 0; u < 4; ++u) {
    int row = u * 64 + (tid >> 3);
    int sc = (tid & 7) ^ (row & 7);
    const float* g = X + (size_t)(row0 + row) * ldk + k0 + sc * 8;
    v[u][0] = *(const f32x4*)g;
    v[u][1] = *(const f32x4*)(g + 4);
  }
}

__device__ __forceinline__ void stageA_write_bf16(const f32x4 (&v)[4][2], char* region,
                                                  int tid) {
#pragma unroll
  for (int u = 0; u < 4; ++u) {
    int d = u * 8192 + tid * 16;
    bf16x8 o;
    o[0] = (short)f2bf(v[u][0][0]); o[1] = (short)f2bf(v[u][0][1]);
    o[2] = (short)f2bf(v[u][0][2]); o[3] = (short)f2bf(v[u][0][3]);
    o[4] = (short)f2bf(v[u][1][0]); o[5] = (short)f2bf(v[u][1][1]);
    o[6] = (short)f2bf(v[u][1][2]); o[7] = (short)f2bf(v[u][1][3]);
    *(bf16x8*)(region + d) = o;
  }
}

// ---------------------------------------------------------------- GEMM1: xp = bf16(x) @ w_inT + b_in   (fused f32->bf16 cast)
// R15 skeleton; change: A cvt+ds_write moved BETWEEN kh halves so it hides under
// kh=1's 32 MFMA (writes->nb, reads<-cb: no alias; f32 loads have ~2400cyc to land).
__global__ __launch_bounds__(512, 1) void gemm1_bf16_k(
    const float* __restrict__ X, const bf16* __restrict__ BT,
    bf16* __restrict__ C, const float* __restrict__ bias, int M, int N, int K) {
  __shared__ char lds[131072];
  const int tid = threadIdx.x, lane = tid & 63, w = tid >> 6;
  const int wr = w >> 2, wc = w & 3;  // 2M x 4N, per-wave 128x64
  const int tm = blockIdx.x * 256, tn = blockIdx.y * 256;
  const int lr = lane & 15;
  const int lc = lane >> 4;
  const int NT = K >> 6;  // 32

  f32x4 acc[8][4] = {};

  {  // prologue: tile 0
    f32x4 av[4][2];
    stageA_load_f32(X, K, tm, 0, tid, av);
    stage_row_bf16(BT, K, tn, 0, lds + 32768, tid);
    stageA_write_bf16(av, lds + 0, tid);
    __syncthreads();
  }

  for (int t = 0; t < NT; ++t) {
    const char* cb = lds + (t & 1) * 65536;
    char* nb = lds + ((t + 1) & 1) * 65536;
    const bool pf = (t + 1 < NT);
    f32x4 av[4][2];
    if (pf) {
      stageA_load_f32(X, K, tm, (t + 1) * 64, tid, av);      // issue early
      stage_row_bf16(BT, K, tn, (t + 1) * 64, nb + 32768, tid);
    }
    {  // kh = 0
      bf16x8 a[8], b[4];
#pragma unroll
      for (int j = 0; j < 4; ++j)
        b[j] = *(const bf16x8*)swz(cb + 32768, wc * 64 + j * 16 + lr, lc);
#pragma unroll
      for (int i = 0; i < 8; ++i)
        a[i] = *(const bf16x8*)swz(cb, wr * 128 + i * 16 + lr, lc);
      __builtin_amdgcn_s_setprio(1);
#pragma unroll
      for (int i = 0; i < 8; ++i)
#pragma unroll
        for (int j = 0; j < 4; ++j)
          acc[i][j] = __builtin_amdgcn_mfma_f32_16x16x32_bf16(a[i], b[j], acc[i][j], 0, 0, 0);
      __builtin_amdgcn_s_setprio(0);
    }
    if (pf) stageA_write_bf16(av, nb, tid);  // cvt+write hides under kh=1 MFMA
    {  // kh = 1
      const int c16 = lc + 4;
      bf16x8 a[8], b[4];
#pragma unroll
      for (int j = 0; j < 4; ++j)
        b[j] = *(const bf16x8*)swz(cb + 32768, wc * 64 + j * 16 + lr, c16);
#pragma unroll
      for (int i = 0; i < 8; ++i)
        a[i] = *(const bf16x8*)swz(cb, wr * 128 + i * 16 + lr, c16);
      __builtin_amdgcn_s_setprio(1);
#pragma unroll
      for (int i = 0; i < 8; ++i)
#pragma unroll
        for (int j = 0; j < 4; ++j)
          acc[i][j] = __builtin_amdgcn_mfma_f32_16x16x32_bf16(a[i], b[j], acc[i][j], 0, 0, 0);
      __builtin_amdgcn_s_setprio(0);
    }
    __syncthreads();  // drains gloads + ds_writes; WAR closed (reads pre-MFMA)
  }

  // epilogue: C/D layout col=lane&15, row=(lane>>4)*4+r  [m89]
#pragma unroll
  for (int i = 0; i < 8; ++i) {
    int m0 = tm + wr * 128 + i * 16 + (lane >> 4) * 4;
#pragma unroll
    for (int j = 0; j < 4; ++j) {
      int n = tn + wc * 64 + j * 16 + (lane & 15);
      float bb = bias[n];
#pragma unroll
      for (int r = 0; r < 4; ++r)
        C[(size_t)(m0 + r) * N + n] = __float2bfloat16(acc[i][j][r] + bb);
    }
  }
}

// ---------------------------------------------------------------- GEMM2: out = x + alpha*(spikes @ w_q8T * scale + b_out)
// i8, 128x256 tile, BK=64, NT=32, 8 waves of 64x64 (2Mx4N), acc[4][4].
// LDS buffer 24KB = A[128][64B]@0 | B[256][64B]@8192; x2 = 48KB -> 2 blocks/CU:
// one block's HBM-heavy epilogue (xres+out stream) overlaps the other's loop.
// (R11's failure of this shape was confounded by scatter staging, fixed in R14.)
__global__ __launch_bounds__(512, 4) void gemm2_i8_k(
    const signed char* __restrict__ A, const signed char* __restrict__ BT,
    float* __restrict__ C, const unsigned int* __restrict__ maxbits,
    const float* __restrict__ bias, const float* __restrict__ xres,
    const float* __restrict__ alpha_p, int M, int N, int K) {
  __shared__ char lds[49152];
  const int tid = threadIdx.x, lane = tid & 63, w = tid >> 6;
  const int wr = w >> 2, wc = w & 3;  // 2M x 4N of 64x64
  const int tm = blockIdx.x * 128, tn = blockIdx.y * 256;
  const int lr = lane & 15;
  const int lc = lane >> 4;  // 0..3
  const int NT = K >> 6;     // 32

  i32x4 acc[4][4] = {};

  stageA_i8_64(A,  K, tm, 0, lds + 0,    tid);
  stageB_i8_64(BT, K, tn, 0, lds + 8192, tid);
  __syncthreads();

  for (int t = 0; t < NT; ++t) {
    const char* cb = lds + (t & 1) * 24576;
    char* nb = lds + ((t + 1) & 1) * 24576;
    if (t + 1 < NT) {  // block-uniform
      stageA_i8_64(A,  K, tm, (t + 1) * 64, nb + 0,    tid);
      stageB_i8_64(BT, K, tn, (t + 1) * 64, nb + 8192, tid);
    }
    i32x4 a[4], b[4];
#pragma unroll
    for (int j = 0; j < 4; ++j)
      b[j] = *(const i32x4*)swz64(cb + 8192, wc * 64 + j * 16 + lr, lc);
#pragma unroll
    for (int i = 0; i < 4; ++i)
      a[i] = *(const i32x4*)swz64(cb, wr * 64 + i * 16 + lr, lc);
    __builtin_amdgcn_s_setprio(1);
#pragma unroll
    for (int i = 0; i < 4; ++i)
#pragma unroll
      for (int j = 0; j < 4; ++j)
        acc[i][j] = __builtin_amdgcn_mfma_i32_16x16x64_i8(a[i], b[j], acc[i][j], 0, 0, 0);
    __builtin_amdgcn_s_setprio(0);
    __syncthreads();
  }

  // epilogue: out = x + alpha*(acc*scale[n] + b_out[n]); scale = maxbits/127
  float alpha = *alpha_p;
#pragma unroll
  for (int i = 0; i < 4; ++i) {
    int m0 = tm + wr * 64 + i * 16 + (lane >> 4) * 4;
#pragma unroll
    for (int j = 0; j < 4; ++j) {
      int n = tn + wc * 64 + j * 16 + (lane & 15);
      float sc = __uint_as_float(maxbits[n]) * (1.f / 127.f);
      float bb = bias[n];
#pragma unroll
      for (int r = 0; r < 4; ++r) {
        size_t idx = (size_t)(m0 + r) * N + n;
        C[idx] = xres[idx] + alpha * ((float)acc[i][j][r] * sc + bb);
      }
    }
  }
}

// ---------------------------------------------------------------- chunked LIF scan (bf16 in, u8 out)
__global__ void snn_scan_k(const bf16* __restrict__ xp, unsigned char* __restrict__ sp,
                           const float* __restrict__ thre_p,
                           int T, int H, int CHUNK, int WARM) {
  int h = blockIdx.x * blockDim.x + threadIdx.x;
  int b = blockIdx.y;
  int c = blockIdx.z;
  float thre = *thre_p;
  float l1 = thre, l2 = 2.f * thre, l3 = 3.f * thre, l4 = 4.f * thre;
  int t0 = c * CHUNK;
  int tw = t0 - WARM;
  if (tw < 0) tw = 0;
  const bf16* xcol = xp + (size_t)b * T * H + h;
  unsigned char* scol = sp + (size_t)b * T * H + h;
  float mem = 0.f;
  for (int t = tw; t < t0; ++t) {  // warmup (state error ~0.25^WARM)
    float xv = __bfloat162float(xcol[(size_t)t * H]);
    mem = DECAY * mem + xv;
    int s = (mem >= l1) + (mem >= l2) + (mem >= l3) + (mem >= l4);
    mem -= (float)s * thre;
  }
  for (int t = t0; t < t0 + CHUNK; ++t) {
    float xv = __bfloat162float(xcol[(size_t)t * H]);
    mem = DECAY * mem + xv;
    int s = (mem >= l1) + (mem >= l2) + (mem >= l3) + (mem >= l4);
    mem -= (float)s * thre;
    scol[(size_t)t * H] = (unsigned char)s;
  }
}

// ---------------------------------------------------------------- launch
extern "C" void kernel_launch(void* const* d_in, const int* in_sizes, int n_in,
                              void* d_out, int out_size, void* d_ws, size_t ws_size,
                              hipStream_t stream) {
  const float* x     = (const float*)d_in[0];
  const float* alpha = (const float*)d_in[1];
  const float* thre  = (const float*)d_in[2];
  const float* w_in  = (const float*)d_in[3];
  const float* b_in  = (const float*)d_in[4];
  const float* w_out = (const float*)d_in[5];
  const float* b_out = (const float*)d_in[6];
  float* out = (float*)d_out;

  const int B = 4, T = 2048, H = 2048;
  const int M = B * T;  // 8192
  const int K = H, N = H;

  char* ws = (char*)d_ws;
  size_t off = 0;
  signed char* spikes = (signed char*)(ws + off); off += (size_t)M * K;      // 16.8MB
  bf16* w_inT   = (bf16*)(ws + off);              off += (size_t)K * N * 2;  // 8.4MB
  signed char* w_q8T = (signed char*)(ws + off);  off += (size_t)K * N;      // 4.2MB
  unsigned int* qmaxbits = (unsigned int*)(ws + off); off += (size_t)N * 4;
  bf16* xp      = (bf16*)(ws + off);              off += (size_t)M * K * 2;  // 33.5MB

  dim3 tb(32, 8);
  dim3 tg(N / 32, K / 32);
  transpose_cast_k<<<tg, tb, 0, stream>>>(w_in, w_inT, N);

  hipMemsetAsync(qmaxbits, 0, (size_t)N * 4, stream);
  const int KCH = 128;
  dim3 cg(N / 256, K / KCH);
  colmax_part_k<<<cg, 256, 0, stream>>>(w_out, qmaxbits, N, KCH);
  transpose_quant_k<<<tg, tb, 0, stream>>>(w_out, qmaxbits, w_q8T, N, K);

  dim3 gg1(M / 256, N / 256);  // 32 x 8 = 256 blocks
  gemm1_bf16_k<<<gg1, 512, 0, stream>>>(x, w_inT, xp, b_in, M, N, K);

  const int CHUNK = 256, WARM = 32, NC = T / CHUNK;
  dim3 sg(H / 256, B, NC);
  snn_scan_k<<<sg, 256, 0, stream>>>(xp, (unsigned char*)spikes, thre, T, H, CHUNK, WARM);

  dim3 gg2(M / 128, N / 256);  // 64 x 8 = 512 blocks = 2/CU
  gemm2_i8_k<<<gg2, 512, 0, stream>>>(spikes, w_q8T, out, qmaxbits, b_out, x, alpha, M, N, K);
}

// Round 17
// 217.346 us; speedup vs baseline: 1.1459x; 1.1459x over previous
//
#include <hip/hip_runtime.h>
#include <hip/hip_bf16.h>

using bf16 = __hip_bfloat16;
typedef __attribute__((ext_vector_type(8))) short bf16x8;
typedef __attribute__((ext_vector_type(4))) float f32x4;
typedef __attribute__((ext_vector_type(4))) int i32x4;

#define DECAY 0.25f

// ---------------------------------------------------------------- helpers
__device__ __forceinline__ void gload_lds16(const void* g, void* l) {
  __builtin_amdgcn_global_load_lds(
      (const __attribute__((address_space(1))) void*)g,
      (__attribute__((address_space(3))) void*)l, 16, 0, 0);
}

__device__ __forceinline__ unsigned short f2bf(float f) {
  __hip_bfloat16 h = __float2bfloat16(f);
  return *reinterpret_cast<unsigned short*>(&h);
}

// ---------------------------------------------------------------- prep kernels
__global__ void transpose_cast_k(const float* __restrict__ w, bf16* __restrict__ wt, int N) {
  __shared__ float t[32][33];
  int bx = blockIdx.x * 32, by = blockIdx.y * 32;
  int tx = threadIdx.x, ty = threadIdx.y;  // block (32,8)
#pragma unroll
  for (int i = 0; i < 32; i += 8)
    t[ty + i][tx] = w[(size_t)(by + ty + i) * N + bx + tx];
  __syncthreads();
#pragma unroll
  for (int i = 0; i < 32; i += 8)
    wt[(size_t)(bx + ty + i) * N + by + tx] = __float2bfloat16(t[tx][ty + i]);
}

// stage 1: per-(k-slab, n) partial absmax -> plain store (no init/atomic needed)
__global__ void colmax_part_k(const float* __restrict__ w, float* __restrict__ partials,
                              int N, int KCH) {
  int n = blockIdx.x * blockDim.x + threadIdx.x;
  int k0 = blockIdx.y * KCH;
  float mx = 0.f;
  for (int k = k0; k < k0 + KCH; ++k) mx = fmaxf(mx, fabsf(w[(size_t)k * N + n]));
  partials[(size_t)blockIdx.y * N + n] = mx;
}

// stage 2: reduce 16 partials in-LDS, quantize w_out -> w_q8T, emit qscale[n]
__global__ void transpose_quant_k(const float* __restrict__ w,
                                  const float* __restrict__ partials,
                                  signed char* __restrict__ wq,
                                  float* __restrict__ qscale, int N, int K, int NSLAB) {
  __shared__ float t[32][33];
  __shared__ float smx[32];
  int bx = blockIdx.x * 32, by = blockIdx.y * 32;  // bx: n-range, by: k-range
  int tx = threadIdx.x, ty = threadIdx.y;          // block (32,8)
  if (ty == 0) {  // 32 threads: reduce the 16 slab-partials for this block's n's
    float mx = 0.f;
    for (int s = 0; s < NSLAB; ++s) mx = fmaxf(mx, partials[(size_t)s * N + bx + tx]);
    smx[tx] = mx;
    if (blockIdx.y == 0) qscale[bx + tx] = mx * (1.f / 127.f);
  }
#pragma unroll
  for (int i = 0; i < 32; i += 8)
    t[ty + i][tx] = w[(size_t)(by + ty + i) * N + bx + tx];
  __syncthreads();
#pragma unroll
  for (int i = 0; i < 32; i += 8) {
    int nl = ty + i;
    float mx = smx[nl];
    float inv = (mx > 0.f) ? 127.f / mx : 0.f;
    int q = __float2int_rn(t[tx][nl] * inv);
    q = max(-127, min(127, q));
    wq[(size_t)(bx + nl) * K + by + tx] = (signed char)q;
  }
}

// ---------------------------------------------------------------- staging: ROW-MAJOR + XOR pre-swizzled source (R14, verified)
// 128B-row region [256][128B]: byte row*128 + c16*16 holds
// src[row0+row][k0 + (c16^(row&7))*E ..+E]  (bf16 E=8, i8 E=16). LINEAR LDS dest.
__device__ __forceinline__ void stage_row_bf16(const bf16* __restrict__ src, int ldk,
                                               int row0, int k0, char* region, int tid) {
#pragma unroll
  for (int u = 0; u < 4; ++u) {
    int d = tid * 16 + u * 8192;
    int row = d >> 7;
    int sc = ((d >> 4) & 7) ^ (row & 7);
    const bf16* g = src + (size_t)(row0 + row) * ldk + k0 + sc * 8;
    gload_lds16(g, region + d);
  }
}

__device__ __forceinline__ void stage_row_i8(const signed char* __restrict__ src, int ldk,
                                             int row0, int k0, char* region, int tid) {
#pragma unroll
  for (int u = 0; u < 4; ++u) {
    int d = tid * 16 + u * 8192;
    int row = d >> 7;
    int sc = ((d >> 4) & 7) ^ (row & 7);
    const signed char* g = src + (size_t)(row0 + row) * ldk + k0 + sc * 16;
    gload_lds16(g, region + d);
  }
}

// swizzled read address for 128B-row regions
__device__ __forceinline__ const char* swz(const char* region, int r, int c16) {
  return region + r * 128 + (((c16 ^ (r & 7)) & 7) << 4);
}

// ---------------------------------------------------------------- A reg-stage from f32 x (fused cast; R15, verified)
__device__ __forceinline__ void stageA_load_f32(const float* __restrict__ X, int ldk,
                                                int row0, int k0, int tid,
                                                f32x4 (&v)[4][2]) {
#pragma unroll
  for (int u = 0; u < 4; ++u) {
    int row = u * 64 + (tid >> 3);
    int sc = (tid & 7) ^ (row & 7);
    const float* g = X + (size_t)(row0 + row) * ldk + k0 + sc * 8;
    v[u][0] = *(const f32x4*)g;
    v[u][1] = *(const f32x4*)(g + 4);
  }
}

__device__ __forceinline__ void stageA_write_bf16(const f32x4 (&v)[4][2], char* region,
                                                  int tid) {
#pragma unroll
  for (int u = 0; u < 4; ++u) {
    int d = u * 8192 + tid * 16;
    bf16x8 o;
    o[0] = (short)f2bf(v[u][0][0]); o[1] = (short)f2bf(v[u][0][1]);
    o[2] = (short)f2bf(v[u][0][2]); o[3] = (short)f2bf(v[u][0][3]);
    o[4] = (short)f2bf(v[u][1][0]); o[5] = (short)f2bf(v[u][1][1]);
    o[6] = (short)f2bf(v[u][1][2]); o[7] = (short)f2bf(v[u][1][3]);
    *(bf16x8*)(region + d) = o;
  }
}

// ---------------------------------------------------------------- GEMM1: xp = bf16(x) @ w_inT + b_in   (fused f32->bf16 cast)
// 256x256 tile, BK=64, 8 waves (2Mx4N, per-wave 128x64), full-drain dbuf.
// A cvt+ds_write sits between kh halves (hides under kh=1 MFMA; writes->nb, reads<-cb).
__global__ __launch_bounds__(512, 1) void gemm1_bf16_k(
    const float* __restrict__ X, const bf16* __restrict__ BT,
    bf16* __restrict__ C, const float* __restrict__ bias, int M, int N, int K) {
  __shared__ char lds[131072];
  const int tid = threadIdx.x, lane = tid & 63, w = tid >> 6;
  const int wr = w >> 2, wc = w & 3;  // 2M x 4N, per-wave 128x64
  const int tm = blockIdx.x * 256, tn = blockIdx.y * 256;
  const int lr = lane & 15;
  const int lc = lane >> 4;
  const int NT = K >> 6;  // 32

  f32x4 acc[8][4] = {};

  {  // prologue: tile 0
    f32x4 av[4][2];
    stageA_load_f32(X, K, tm, 0, tid, av);
    stage_row_bf16(BT, K, tn, 0, lds + 32768, tid);
    stageA_write_bf16(av, lds + 0, tid);
    __syncthreads();
  }

  for (int t = 0; t < NT; ++t) {
    const char* cb = lds + (t & 1) * 65536;
    char* nb = lds + ((t + 1) & 1) * 65536;
    const bool pf = (t + 1 < NT);
    f32x4 av[4][2];
    if (pf) {
      stageA_load_f32(X, K, tm, (t + 1) * 64, tid, av);      // issue early
      stage_row_bf16(BT, K, tn, (t + 1) * 64, nb + 32768, tid);
    }
    {  // kh = 0
      bf16x8 a[8], b[4];
#pragma unroll
      for (int j = 0; j < 4; ++j)
        b[j] = *(const bf16x8*)swz(cb + 32768, wc * 64 + j * 16 + lr, lc);
#pragma unroll
      for (int i = 0; i < 8; ++i)
        a[i] = *(const bf16x8*)swz(cb, wr * 128 + i * 16 + lr, lc);
      __builtin_amdgcn_s_setprio(1);
#pragma unroll
      for (int i = 0; i < 8; ++i)
#pragma unroll
        for (int j = 0; j < 4; ++j)
          acc[i][j] = __builtin_amdgcn_mfma_f32_16x16x32_bf16(a[i], b[j], acc[i][j], 0, 0, 0);
      __builtin_amdgcn_s_setprio(0);
    }
    if (pf) stageA_write_bf16(av, nb, tid);  // cvt+write hides under kh=1 MFMA
    {  // kh = 1
      const int c16 = lc + 4;
      bf16x8 a[8], b[4];
#pragma unroll
      for (int j = 0; j < 4; ++j)
        b[j] = *(const bf16x8*)swz(cb + 32768, wc * 64 + j * 16 + lr, c16);
#pragma unroll
      for (int i = 0; i < 8; ++i)
        a[i] = *(const bf16x8*)swz(cb, wr * 128 + i * 16 + lr, c16);
      __builtin_amdgcn_s_setprio(1);
#pragma unroll
      for (int i = 0; i < 8; ++i)
#pragma unroll
        for (int j = 0; j < 4; ++j)
          acc[i][j] = __builtin_amdgcn_mfma_f32_16x16x32_bf16(a[i], b[j], acc[i][j], 0, 0, 0);
      __builtin_amdgcn_s_setprio(0);
    }
    __syncthreads();  // drains gloads + ds_writes; WAR closed (reads pre-MFMA)
  }

  // epilogue: C/D layout col=lane&15, row=(lane>>4)*4+r  [m89]
#pragma unroll
  for (int i = 0; i < 8; ++i) {
    int m0 = tm + wr * 128 + i * 16 + (lane >> 4) * 4;
#pragma unroll
    for (int j = 0; j < 4; ++j) {
      int n = tn + wc * 64 + j * 16 + (lane & 15);
      float bb = bias[n];
#pragma unroll
      for (int r = 0; r < 4; ++r)
        C[(size_t)(m0 + r) * N + n] = __float2bfloat16(acc[i][j][r] + bb);
    }
  }
}

// ---------------------------------------------------------------- GEMM2: out = x + alpha*(spikes @ w_q8T * scale + b_out)
// i8, 256x256 tile, BK=128, NT=16, row-major swizzled staging (R14/R15, measured-good).
__global__ __launch_bounds__(512, 1) void gemm2_i8_k(
    const signed char* __restrict__ A, const signed char* __restrict__ BT,
    float* __restrict__ C, const float* __restrict__ qscale,
    const float* __restrict__ bias, const float* __restrict__ xres,
    const float* __restrict__ alpha_p, int M, int N, int K) {
  __shared__ char lds[131072];
  const int tid = threadIdx.x, lane = tid & 63, w = tid >> 6;
  const int wr = w >> 2, wc = w & 3;
  const int tm = blockIdx.x * 256, tn = blockIdx.y * 256;
  const int lr = lane & 15;
  const int lc = lane >> 4;
  const int NT = K >> 7;  // 16

  i32x4 acc[8][4] = {};

  stage_row_i8(A,  K, tm, 0, lds + 0,     tid);
  stage_row_i8(BT, K, tn, 0, lds + 32768, tid);
  __syncthreads();

  for (int t = 0; t < NT; ++t) {
    const char* cb = lds + (t & 1) * 65536;
    char* nb = lds + ((t + 1) & 1) * 65536;
    if (t + 1 < NT) {
      stage_row_i8(A,  K, tm, (t + 1) * 128, nb + 0,     tid);
      stage_row_i8(BT, K, tn, (t + 1) * 128, nb + 32768, tid);
    }
#pragma unroll
    for (int kh = 0; kh < 2; ++kh) {
      const int c16 = lc + kh * 4;
      i32x4 a[8], b[4];
#pragma unroll
      for (int j = 0; j < 4; ++j)
        b[j] = *(const i32x4*)swz(cb + 32768, wc * 64 + j * 16 + lr, c16);
#pragma unroll
      for (int i = 0; i < 8; ++i)
        a[i] = *(const i32x4*)swz(cb, wr * 128 + i * 16 + lr, c16);
      __builtin_amdgcn_s_setprio(1);
#pragma unroll
      for (int i = 0; i < 8; ++i)
#pragma unroll
        for (int j = 0; j < 4; ++j)
          acc[i][j] = __builtin_amdgcn_mfma_i32_16x16x64_i8(a[i], b[j], acc[i][j], 0, 0, 0);
      __builtin_amdgcn_s_setprio(0);
    }
    __syncthreads();
  }

  // epilogue: out = x + alpha*(acc*scale[n] + b_out[n])
  float alpha = *alpha_p;
#pragma unroll
  for (int i = 0; i < 8; ++i) {
    int m0 = tm + wr * 128 + i * 16 + (lane >> 4) * 4;
#pragma unroll
    for (int j = 0; j < 4; ++j) {
      int n = tn + wc * 64 + j * 16 + (lane & 15);
      float sc = qscale[n];
      float bb = bias[n];
#pragma unroll
      for (int r = 0; r < 4; ++r) {
        size_t idx = (size_t)(m0 + r) * N + n;
        C[idx] = xres[idx] + alpha * ((float)acc[i][j][r] * sc + bb);
      }
    }
  }
}

// ---------------------------------------------------------------- chunked LIF scan (bf16 in, u8 out)
__global__ void snn_scan_k(const bf16* __restrict__ xp, unsigned char* __restrict__ sp,
                           const float* __restrict__ thre_p,
                           int T, int H, int CHUNK, int WARM) {
  int h = blockIdx.x * blockDim.x + threadIdx.x;
  int b = blockIdx.y;
  int c = blockIdx.z;
  float thre = *thre_p;
  float l1 = thre, l2 = 2.f * thre, l3 = 3.f * thre, l4 = 4.f * thre;
  int t0 = c * CHUNK;
  int tw = t0 - WARM;
  if (tw < 0) tw = 0;
  const bf16* xcol = xp + (size_t)b * T * H + h;
  unsigned char* scol = sp + (size_t)b * T * H + h;
  float mem = 0.f;
  for (int t = tw; t < t0; ++t) {  // warmup (state error ~0.25^WARM)
    float xv = __bfloat162float(xcol[(size_t)t * H]);
    mem = DECAY * mem + xv;
    int s = (mem >= l1) + (mem >= l2) + (mem >= l3) + (mem >= l4);
    mem -= (float)s * thre;
  }
  for (int t = t0; t < t0 + CHUNK; ++t) {
    float xv = __bfloat162float(xcol[(size_t)t * H]);
    mem = DECAY * mem + xv;
    int s = (mem >= l1) + (mem >= l2) + (mem >= l3) + (mem >= l4);
    mem -= (float)s * thre;
    scol[(size_t)t * H] = (unsigned char)s;
  }
}

// ---------------------------------------------------------------- launch
extern "C" void kernel_launch(void* const* d_in, const int* in_sizes, int n_in,
                              void* d_out, int out_size, void* d_ws, size_t ws_size,
                              hipStream_t stream) {
  const float* x     = (const float*)d_in[0];
  const float* alpha = (const float*)d_in[1];
  const float* thre  = (const float*)d_in[2];
  const float* w_in  = (const float*)d_in[3];
  const float* b_in  = (const float*)d_in[4];
  const float* w_out = (const float*)d_in[5];
  const float* b_out = (const float*)d_in[6];
  float* out = (float*)d_out;

  const int B = 4, T = 2048, H = 2048;
  const int M = B * T;  // 8192
  const int K = H, N = H;
  const int NSLAB = 16;

  char* ws = (char*)d_ws;
  size_t off = 0;
  signed char* spikes = (signed char*)(ws + off); off += (size_t)M * K;      // 16.8MB
  bf16* w_inT   = (bf16*)(ws + off);              off += (size_t)K * N * 2;  // 8.4MB
  signed char* w_q8T = (signed char*)(ws + off);  off += (size_t)K * N;      // 4.2MB
  float* partials = (float*)(ws + off);           off += (size_t)NSLAB * N * 4;  // 128KB
  float* qscale  = (float*)(ws + off);            off += (size_t)N * 4;
  bf16* xp      = (bf16*)(ws + off);              off += (size_t)M * K * 2;  // 33.5MB

  dim3 tb(32, 8);
  dim3 tg(N / 32, K / 32);
  transpose_cast_k<<<tg, tb, 0, stream>>>(w_in, w_inT, N);

  const int KCH = K / NSLAB;  // 128
  dim3 cg(N / 256, NSLAB);
  colmax_part_k<<<cg, 256, 0, stream>>>(w_out, partials, N, KCH);
  transpose_quant_k<<<tg, tb, 0, stream>>>(w_out, partials, w_q8T, qscale, N, K, NSLAB);

  dim3 gg1(M / 256, N / 256);  // 32 x 8 = 256 blocks
  gemm1_bf16_k<<<gg1, 512, 0, stream>>>(x, w_inT, xp, b_in, M, N, K);

  const int CHUNK = 128, WARM = 32, NC = T / CHUNK;
  dim3 sg(H / 256, B, NC);
  snn_scan_k<<<sg, 256, 0, stream>>>(xp, (unsigned char*)spikes, thre, T, H, CHUNK, WARM);

  gemm2_i8_k<<<gg1, 512, 0, stream>>>(spikes, w_q8T, out, qscale, b_out, x, alpha, M, N, K);
}

// Round 18
// 210.673 us; speedup vs baseline: 1.1822x; 1.0317x over previous
//
#include <hip/hip_runtime.h>
#include <hip/hip_bf16.h>

using bf16 = __hip_bfloat16;
typedef __attribute__((ext_vector_type(8))) short bf16x8;
typedef __attribute__((ext_vector_type(4))) float f32x4;
typedef __attribute__((ext_vector_type(4))) int i32x4;

#define DECAY 0.25f

// ---------------------------------------------------------------- helpers
__device__ __forceinline__ void gload_lds16(const void* g, void* l) {
  __builtin_amdgcn_global_load_lds(
      (const __attribute__((address_space(1))) void*)g,
      (__attribute__((address_space(3))) void*)l, 16, 0, 0);
}

__device__ __forceinline__ unsigned short f2bf(float f) {
  __hip_bfloat16 h = __float2bfloat16(f);
  return *reinterpret_cast<unsigned short*>(&h);
}

// ---------------------------------------------------------------- prep kernels
__global__ void transpose_cast_k(const float* __restrict__ w, bf16* __restrict__ wt, int N) {
  __shared__ float t[32][33];
  int bx = blockIdx.x * 32, by = blockIdx.y * 32;
  int tx = threadIdx.x, ty = threadIdx.y;  // block (32,8)
#pragma unroll
  for (int i = 0; i < 32; i += 8)
    t[ty + i][tx] = w[(size_t)(by + ty + i) * N + bx + tx];
  __syncthreads();
#pragma unroll
  for (int i = 0; i < 32; i += 8)
    wt[(size_t)(bx + ty + i) * N + by + tx] = __float2bfloat16(t[tx][ty + i]);
}

// stage 1: per-(k-slab, n) partial absmax -> plain store (no init/atomic needed)
__global__ void colmax_part_k(const float* __restrict__ w, float* __restrict__ partials,
                              int N, int KCH) {
  int n = blockIdx.x * blockDim.x + threadIdx.x;
  int k0 = blockIdx.y * KCH;
  float mx = 0.f;
  for (int k = k0; k < k0 + KCH; ++k) mx = fmaxf(mx, fabsf(w[(size_t)k * N + n]));
  partials[(size_t)blockIdx.y * N + n] = mx;
}

// stage 2: reduce slab partials in-LDS, quantize w_out -> w_q8T, emit qscale[n]
__global__ void transpose_quant_k(const float* __restrict__ w,
                                  const float* __restrict__ partials,
                                  signed char* __restrict__ wq,
                                  float* __restrict__ qscale, int N, int K, int NSLAB) {
  __shared__ float t[32][33];
  __shared__ float smx[32];
  int bx = blockIdx.x * 32, by = blockIdx.y * 32;  // bx: n-range, by: k-range
  int tx = threadIdx.x, ty = threadIdx.y;          // block (32,8)
  if (ty == 0) {
    float mx = 0.f;
    for (int s = 0; s < NSLAB; ++s) mx = fmaxf(mx, partials[(size_t)s * N + bx + tx]);
    smx[tx] = mx;
    if (blockIdx.y == 0) qscale[bx + tx] = mx * (1.f / 127.f);
  }
#pragma unroll
  for (int i = 0; i < 32; i += 8)
    t[ty + i][tx] = w[(size_t)(by + ty + i) * N + bx + tx];
  __syncthreads();
#pragma unroll
  for (int i = 0; i < 32; i += 8) {
    int nl = ty + i;
    float mx = smx[nl];
    float inv = (mx > 0.f) ? 127.f / mx : 0.f;
    int q = __float2int_rn(t[tx][nl] * inv);
    q = max(-127, min(127, q));
    wq[(size_t)(bx + nl) * K + by + tx] = (signed char)q;
  }
}

// ---------------------------------------------------------------- staging: ROW-MAJOR + XOR pre-swizzled source (R14, verified)
// 128B-row region [256][128B]: byte row*128 + c16*16 holds
// src[row0+row][k0 + (c16^(row&7))*E ..+E]  (bf16 E=8, i8 E=16). LINEAR LDS dest,
// permutation in the global source; reads apply the same XOR (<=2-way aliasing, free).
__device__ __forceinline__ void stage_row_bf16(const bf16* __restrict__ src, int ldk,
                                               int row0, int k0, char* region, int tid) {
#pragma unroll
  for (int u = 0; u < 4; ++u) {
    int d = tid * 16 + u * 8192;
    int row = d >> 7;
    int sc = ((d >> 4) & 7) ^ (row & 7);
    const bf16* g = src + (size_t)(row0 + row) * ldk + k0 + sc * 8;
    gload_lds16(g, region + d);
  }
}

__device__ __forceinline__ void stage_row_i8(const signed char* __restrict__ src, int ldk,
                                             int row0, int k0, char* region, int tid) {
#pragma unroll
  for (int u = 0; u < 4; ++u) {
    int d = tid * 16 + u * 8192;
    int row = d >> 7;
    int sc = ((d >> 4) & 7) ^ (row & 7);
    const signed char* g = src + (size_t)(row0 + row) * ldk + k0 + sc * 16;
    gload_lds16(g, region + d);
  }
}

__device__ __forceinline__ const char* swz(const char* region, int r, int c16) {
  return region + r * 128 + (((c16 ^ (r & 7)) & 7) << 4);
}

// ---------------------------------------------------------------- A reg-stage from f32 x (fused cast; R15-measured)
// Pass u: row = u*64 + tid>>3, dest chunk = tid&7, src chunk = (tid&7)^(row&7).
// 8 consecutive lanes cover one row's contiguous 256B f32 -> coalesced; ds_write_b128
// lane-consecutive -> conflict-free; produces the exact stage_row_bf16 LDS image.
__device__ __forceinline__ void stageA_load_f32(const float* __restrict__ X, int ldk,
                                                int row0, int k0, int tid,
                                                f32x4 (&v)[4][2]) {
#pragma unroll
  for (int u = 0; u < 4; ++u) {
    int row = u * 64 + (tid >> 3);
    int sc = (tid & 7) ^ (row & 7);
    const float* g = X + (size_t)(row0 + row) * ldk + k0 + sc * 8;
    v[u][0] = *(const f32x4*)g;
    v[u][1] = *(const f32x4*)(g + 4);
  }
}

__device__ __forceinline__ void stageA_write_bf16(const f32x4 (&v)[4][2], char* region,
                                                  int tid) {
#pragma unroll
  for (int u = 0; u < 4; ++u) {
    int d = u * 8192 + tid * 16;
    bf16x8 o;
    o[0] = (short)f2bf(v[u][0][0]); o[1] = (short)f2bf(v[u][0][1]);
    o[2] = (short)f2bf(v[u][0][2]); o[3] = (short)f2bf(v[u][0][3]);
    o[4] = (short)f2bf(v[u][1][0]); o[5] = (short)f2bf(v[u][1][1]);
    o[6] = (short)f2bf(v[u][1][2]); o[7] = (short)f2bf(v[u][1][3]);
    *(bf16x8*)(region + d) = o;
  }
}

// ---------------------------------------------------------------- GEMM1: xp = bf16(x) @ w_inT + b_in   (fused f32->bf16 cast)
// 256x256 tile, BK=64, 8 waves (2Mx4N, per-wave 128x64), full-drain dbuf.
// EXACT 213.1us-measured variant: A loads at loop top; cvt+ds_write AFTER both
// kh MFMA clusters, before the barrier.
__global__ __launch_bounds__(512, 1) void gemm1_bf16_k(
    const float* __restrict__ X, const bf16* __restrict__ BT,
    bf16* __restrict__ C, const float* __restrict__ bias, int M, int N, int K) {
  __shared__ char lds[131072];
  const int tid = threadIdx.x, lane = tid & 63, w = tid >> 6;
  const int wr = w >> 2, wc = w & 3;  // 2M x 4N, per-wave 128x64
  const int tm = blockIdx.x * 256, tn = blockIdx.y * 256;
  const int lr = lane & 15;
  const int lc = lane >> 4;
  const int NT = K >> 6;  // 32

  f32x4 acc[8][4] = {};

  {  // prologue: tile 0
    f32x4 av[4][2];
    stageA_load_f32(X, K, tm, 0, tid, av);
    stage_row_bf16(BT, K, tn, 0, lds + 32768, tid);
    stageA_write_bf16(av, lds + 0, tid);
    __syncthreads();
  }

  for (int t = 0; t < NT; ++t) {
    const char* cb = lds + (t & 1) * 65536;
    char* nb = lds + ((t + 1) & 1) * 65536;
    const bool pf = (t + 1 < NT);
    f32x4 av[4][2];
    if (pf) {
      stageA_load_f32(X, K, tm, (t + 1) * 64, tid, av);      // issue early
      stage_row_bf16(BT, K, tn, (t + 1) * 64, nb + 32768, tid);
    }
#pragma unroll
    for (int kh = 0; kh < 2; ++kh) {
      const int c16 = lc + kh * 4;
      bf16x8 a[8], b[4];
#pragma unroll
      for (int j = 0; j < 4; ++j)
        b[j] = *(const bf16x8*)swz(cb + 32768, wc * 64 + j * 16 + lr, c16);
#pragma unroll
      for (int i = 0; i < 8; ++i)
        a[i] = *(const bf16x8*)swz(cb, wr * 128 + i * 16 + lr, c16);
      __builtin_amdgcn_s_setprio(1);
#pragma unroll
      for (int i = 0; i < 8; ++i)
#pragma unroll
        for (int j = 0; j < 4; ++j)
          acc[i][j] = __builtin_amdgcn_mfma_f32_16x16x32_bf16(a[i], b[j], acc[i][j], 0, 0, 0);
      __builtin_amdgcn_s_setprio(0);
    }
    if (pf) stageA_write_bf16(av, nb, tid);  // cvt+write late (loads long landed)
    __syncthreads();  // drains gloads + ds_writes; WAR closed (reads pre-MFMA)
  }

  // epilogue: C/D layout col=lane&15, row=(lane>>4)*4+r  [m89]
#pragma unroll
  for (int i = 0; i < 8; ++i) {
    int m0 = tm + wr * 128 + i * 16 + (lane >> 4) * 4;
#pragma unroll
    for (int j = 0; j < 4; ++j) {
      int n = tn + wc * 64 + j * 16 + (lane & 15);
      float bb = bias[n];
#pragma unroll
      for (int r = 0; r < 4; ++r)
        C[(size_t)(m0 + r) * N + n] = __float2bfloat16(acc[i][j][r] + bb);
    }
  }
}

// ---------------------------------------------------------------- GEMM2: out = x + alpha*(spikes @ w_q8T * scale + b_out)
// i8, 256x256 tile, BK=128, NT=16, row-major swizzled staging (R14/R15, measured-good).
__global__ __launch_bounds__(512, 1) void gemm2_i8_k(
    const signed char* __restrict__ A, const signed char* __restrict__ BT,
    float* __restrict__ C, const float* __restrict__ qscale,
    const float* __restrict__ bias, const float* __restrict__ xres,
    const float* __restrict__ alpha_p, int M, int N, int K) {
  __shared__ char lds[131072];
  const int tid = threadIdx.x, lane = tid & 63, w = tid >> 6;
  const int wr = w >> 2, wc = w & 3;
  const int tm = blockIdx.x * 256, tn = blockIdx.y * 256;
  const int lr = lane & 15;
  const int lc = lane >> 4;
  const int NT = K >> 7;  // 16

  i32x4 acc[8][4] = {};

  stage_row_i8(A,  K, tm, 0, lds + 0,     tid);
  stage_row_i8(BT, K, tn, 0, lds + 32768, tid);
  __syncthreads();

  for (int t = 0; t < NT; ++t) {
    const char* cb = lds + (t & 1) * 65536;
    char* nb = lds + ((t + 1) & 1) * 65536;
    if (t + 1 < NT) {
      stage_row_i8(A,  K, tm, (t + 1) * 128, nb + 0,     tid);
      stage_row_i8(BT, K, tn, (t + 1) * 128, nb + 32768, tid);
    }
#pragma unroll
    for (int kh = 0; kh < 2; ++kh) {
      const int c16 = lc + kh * 4;
      i32x4 a[8], b[4];
#pragma unroll
      for (int j = 0; j < 4; ++j)
        b[j] = *(const i32x4*)swz(cb + 32768, wc * 64 + j * 16 + lr, c16);
#pragma unroll
      for (int i = 0; i < 8; ++i)
        a[i] = *(const i32x4*)swz(cb, wr * 128 + i * 16 + lr, c16);
      __builtin_amdgcn_s_setprio(1);
#pragma unroll
      for (int i = 0; i < 8; ++i)
#pragma unroll
        for (int j = 0; j < 4; ++j)
          acc[i][j] = __builtin_amdgcn_mfma_i32_16x16x64_i8(a[i], b[j], acc[i][j], 0, 0, 0);
      __builtin_amdgcn_s_setprio(0);
    }
    __syncthreads();
  }

  // epilogue: out = x + alpha*(acc*scale[n] + b_out[n])
  float alpha = *alpha_p;
#pragma unroll
  for (int i = 0; i < 8; ++i) {
    int m0 = tm + wr * 128 + i * 16 + (lane >> 4) * 4;
#pragma unroll
    for (int j = 0; j < 4; ++j) {
      int n = tn + wc * 64 + j * 16 + (lane & 15);
      float sc = qscale[n];
      float bb = bias[n];
#pragma unroll
      for (int r = 0; r < 4; ++r) {
        size_t idx = (size_t)(m0 + r) * N + n;
        C[idx] = xres[idx] + alpha * ((float)acc[i][j][r] * sc + bb);
      }
    }
  }
}

// ---------------------------------------------------------------- chunked LIF scan (bf16 in, u8 out)
// WARM=16: warm-start state error 0.25^16 ~ 2e-10 -> spike-flip probability nil.
__global__ void snn_scan_k(const bf16* __restrict__ xp, unsigned char* __restrict__ sp,
                           const float* __restrict__ thre_p,
                           int T, int H, int CHUNK, int WARM) {
  int h = blockIdx.x * blockDim.x + threadIdx.x;
  int b = blockIdx.y;
  int c = blockIdx.z;
  float thre = *thre_p;
  float l1 = thre, l2 = 2.f * thre, l3 = 3.f * thre, l4 = 4.f * thre;
  int t0 = c * CHUNK;
  int tw = t0 - WARM;
  if (tw < 0) tw = 0;
  const bf16* xcol = xp + (size_t)b * T * H + h;
  unsigned char* scol = sp + (size_t)b * T * H + h;
  float mem = 0.f;
  for (int t = tw; t < t0; ++t) {
    float xv = __bfloat162float(xcol[(size_t)t * H]);
    mem = DECAY * mem + xv;
    int s = (mem >= l1) + (mem >= l2) + (mem >= l3) + (mem >= l4);
    mem -= (float)s * thre;
  }
  for (int t = t0; t < t0 + CHUNK; ++t) {
    float xv = __bfloat162float(xcol[(size_t)t * H]);
    mem = DECAY * mem + xv;
    int s = (mem >= l1) + (mem >= l2) + (mem >= l3) + (mem >= l4);
    mem -= (float)s * thre;
    scol[(size_t)t * H] = (unsigned char)s;
  }
}

// ---------------------------------------------------------------- launch
extern "C" void kernel_launch(void* const* d_in, const int* in_sizes, int n_in,
                              void* d_out, int out_size, void* d_ws, size_t ws_size,
                              hipStream_t stream) {
  const float* x     = (const float*)d_in[0];
  const float* alpha = (const float*)d_in[1];
  const float* thre  = (const float*)d_in[2];
  const float* w_in  = (const float*)d_in[3];
  const float* b_in  = (const float*)d_in[4];
  const float* w_out = (const float*)d_in[5];
  const float* b_out = (const float*)d_in[6];
  float* out = (float*)d_out;

  const int B = 4, T = 2048, H = 2048;
  const int M = B * T;  // 8192
  const int K = H, N = H;
  const int NSLAB = 16;

  char* ws = (char*)d_ws;
  size_t off = 0;
  signed char* spikes = (signed char*)(ws + off); off += (size_t)M * K;      // 16.8MB
  bf16* w_inT   = (bf16*)(ws + off);              off += (size_t)K * N * 2;  // 8.4MB
  signed char* w_q8T = (signed char*)(ws + off);  off += (size_t)K * N;      // 4.2MB
  float* partials = (float*)(ws + off);           off += (size_t)NSLAB * N * 4;
  float* qscale  = (float*)(ws + off);            off += (size_t)N * 4;
  bf16* xp      = (bf16*)(ws + off);              off += (size_t)M * K * 2;  // 33.5MB

  dim3 tb(32, 8);
  dim3 tg(N / 32, K / 32);
  transpose_cast_k<<<tg, tb, 0, stream>>>(w_in, w_inT, N);

  const int KCH = K / NSLAB;  // 128
  dim3 cg(N / 256, NSLAB);
  colmax_part_k<<<cg, 256, 0, stream>>>(w_out, partials, N, KCH);
  transpose_quant_k<<<tg, tb, 0, stream>>>(w_out, partials, w_q8T, qscale, N, K, NSLAB);

  dim3 gg1(M / 256, N / 256);  // 32 x 8 = 256 blocks
  gemm1_bf16_k<<<gg1, 512, 0, stream>>>(x, w_inT, xp, b_in, M, N, K);

  const int CHUNK = 128, WARM = 16, NC = T / CHUNK;
  dim3 sg(H / 256, B, NC);
  snn_scan_k<<<sg, 256, 0, stream>>>(xp, (unsigned char*)spikes, thre, T, H, CHUNK, WARM);

  gemm2_i8_k<<<gg1, 512, 0, stream>>>(spikes, w_q8T, out, qscale, b_out, x, alpha, M, N, K);
}

// Round 19
// 210.572 us; speedup vs baseline: 1.1827x; 1.0005x over previous
//
#include <hip/hip_runtime.h>
#include <hip/hip_bf16.h>

using bf16 = __hip_bfloat16;
typedef __attribute__((ext_vector_type(8))) short bf16x8;
typedef __attribute__((ext_vector_type(4))) float f32x4;
typedef __attribute__((ext_vector_type(4))) int i32x4;

#define DECAY 0.25f

// ---------------------------------------------------------------- helpers
__device__ __forceinline__ void gload_lds16(const void* g, void* l) {
  __builtin_amdgcn_global_load_lds(
      (const __attribute__((address_space(1))) void*)g,
      (__attribute__((address_space(3))) void*)l, 16, 0, 0);
}

__device__ __forceinline__ unsigned short f2bf(float f) {
  __hip_bfloat16 h = __float2bfloat16(f);
  return *reinterpret_cast<unsigned short*>(&h);
}

// XCD co-dispatch mapping (bid%8 = XCD round-robin heuristic, m157/m192):
// each XCD owns 4 m-tiles; consecutive blocks on an XCD sweep n for fixed m
// -> A-panel (2MB f32 / 1MB bf16 / 0.5MB i8) stays resident in that XCD's 4MB L2,
// cutting A's L3 traffic by 8x. Bijective: (xcd, loc>>3, loc&7) <-> (tmi, tni).
__device__ __forceinline__ void xcd_tile(int bid, int& tm, int& tn) {
  int xcd = bid & 7, loc = bid >> 3;
  tm = (xcd * 4 + (loc >> 3)) * 256;  // 32 m-tiles
  tn = (loc & 7) * 256;               // 8 n-tiles
}

// ---------------------------------------------------------------- prep kernels
__global__ void transpose_cast_k(const float* __restrict__ w, bf16* __restrict__ wt, int N) {
  __shared__ float t[32][33];
  int bx = blockIdx.x * 32, by = blockIdx.y * 32;
  int tx = threadIdx.x, ty = threadIdx.y;  // block (32,8)
#pragma unroll
  for (int i = 0; i < 32; i += 8)
    t[ty + i][tx] = w[(size_t)(by + ty + i) * N + bx + tx];
  __syncthreads();
#pragma unroll
  for (int i = 0; i < 32; i += 8)
    wt[(size_t)(bx + ty + i) * N + by + tx] = __float2bfloat16(t[tx][ty + i]);
}

__global__ void colmax_part_k(const float* __restrict__ w, float* __restrict__ partials,
                              int N, int KCH) {
  int n = blockIdx.x * blockDim.x + threadIdx.x;
  int k0 = blockIdx.y * KCH;
  float mx = 0.f;
  for (int k = k0; k < k0 + KCH; ++k) mx = fmaxf(mx, fabsf(w[(size_t)k * N + n]));
  partials[(size_t)blockIdx.y * N + n] = mx;
}

__global__ void transpose_quant_k(const float* __restrict__ w,
                                  const float* __restrict__ partials,
                                  signed char* __restrict__ wq,
                                  float* __restrict__ qscale, int N, int K, int NSLAB) {
  __shared__ float t[32][33];
  __shared__ float smx[32];
  int bx = blockIdx.x * 32, by = blockIdx.y * 32;
  int tx = threadIdx.x, ty = threadIdx.y;  // block (32,8)
  if (ty == 0) {
    float mx = 0.f;
    for (int s = 0; s < NSLAB; ++s) mx = fmaxf(mx, partials[(size_t)s * N + bx + tx]);
    smx[tx] = mx;
    if (blockIdx.y == 0) qscale[bx + tx] = mx * (1.f / 127.f);
  }
#pragma unroll
  for (int i = 0; i < 32; i += 8)
    t[ty + i][tx] = w[(size_t)(by + ty + i) * N + bx + tx];
  __syncthreads();
#pragma unroll
  for (int i = 0; i < 32; i += 8) {
    int nl = ty + i;
    float mx = smx[nl];
    float inv = (mx > 0.f) ? 127.f / mx : 0.f;
    int q = __float2int_rn(t[tx][nl] * inv);
    q = max(-127, min(127, q));
    wq[(size_t)(bx + nl) * K + by + tx] = (signed char)q;
  }
}

// ---------------------------------------------------------------- staging (R14, verified)
__device__ __forceinline__ void stage_row_bf16(const bf16* __restrict__ src, int ldk,
                                               int row0, int k0, char* region, int tid) {
#pragma unroll
  for (int u = 0; u < 4; ++u) {
    int d = tid * 16 + u * 8192;
    int row = d >> 7;
    int sc = ((d >> 4) & 7) ^ (row & 7);
    const bf16* g = src + (size_t)(row0 + row) * ldk + k0 + sc * 8;
    gload_lds16(g, region + d);
  }
}

__device__ __forceinline__ void stage_row_i8(const signed char* __restrict__ src, int ldk,
                                             int row0, int k0, char* region, int tid) {
#pragma unroll
  for (int u = 0; u < 4; ++u) {
    int d = tid * 16 + u * 8192;
    int row = d >> 7;
    int sc = ((d >> 4) & 7) ^ (row & 7);
    const signed char* g = src + (size_t)(row0 + row) * ldk + k0 + sc * 16;
    gload_lds16(g, region + d);
  }
}

__device__ __forceinline__ const char* swz(const char* region, int r, int c16) {
  return region + r * 128 + (((c16 ^ (r & 7)) & 7) << 4);
}

// ---------------------------------------------------------------- A reg-stage from f32 x (fused cast; R15-measured)
__device__ __forceinline__ void stageA_load_f32(const float* __restrict__ X, int ldk,
                                                int row0, int k0, int tid,
                                                f32x4 (&v)[4][2]) {
#pragma unroll
  for (int u = 0; u < 4; ++u) {
    int row = u * 64 + (tid >> 3);
    int sc = (tid & 7) ^ (row & 7);
    const float* g = X + (size_t)(row0 + row) * ldk + k0 + sc * 8;
    v[u][0] = *(const f32x4*)g;
    v[u][1] = *(const f32x4*)(g + 4);
  }
}

__device__ __forceinline__ void stageA_write_bf16(const f32x4 (&v)[4][2], char* region,
                                                  int tid) {
#pragma unroll
  for (int u = 0; u < 4; ++u) {
    int d = u * 8192 + tid * 16;
    bf16x8 o;
    o[0] = (short)f2bf(v[u][0][0]); o[1] = (short)f2bf(v[u][0][1]);
    o[2] = (short)f2bf(v[u][0][2]); o[3] = (short)f2bf(v[u][0][3]);
    o[4] = (short)f2bf(v[u][1][0]); o[5] = (short)f2bf(v[u][1][1]);
    o[6] = (short)f2bf(v[u][1][2]); o[7] = (short)f2bf(v[u][1][3]);
    *(bf16x8*)(region + d) = o;
  }
}

// ---------------------------------------------------------------- GEMM1: xp = bf16(x) @ w_inT + b_in   (fused cast; R18 body + XCD map)
__global__ __launch_bounds__(512, 1) void gemm1_bf16_k(
    const float* __restrict__ X, const bf16* __restrict__ BT,
    bf16* __restrict__ C, const float* __restrict__ bias, int M, int N, int K) {
  __shared__ char lds[131072];
  const int tid = threadIdx.x, lane = tid & 63, w = tid >> 6;
  const int wr = w >> 2, wc = w & 3;
  int tm, tn;
  xcd_tile(blockIdx.x, tm, tn);
  const int lr = lane & 15;
  const int lc = lane >> 4;
  const int NT = K >> 6;  // 32

  f32x4 acc[8][4] = {};

  {  // prologue: tile 0
    f32x4 av[4][2];
    stageA_load_f32(X, K, tm, 0, tid, av);
    stage_row_bf16(BT, K, tn, 0, lds + 32768, tid);
    stageA_write_bf16(av, lds + 0, tid);
    __syncthreads();
  }

  for (int t = 0; t < NT; ++t) {
    const char* cb = lds + (t & 1) * 65536;
    char* nb = lds + ((t + 1) & 1) * 65536;
    const bool pf = (t + 1 < NT);
    f32x4 av[4][2];
    if (pf) {
      stageA_load_f32(X, K, tm, (t + 1) * 64, tid, av);
      stage_row_bf16(BT, K, tn, (t + 1) * 64, nb + 32768, tid);
    }
#pragma unroll
    for (int kh = 0; kh < 2; ++kh) {
      const int c16 = lc + kh * 4;
      bf16x8 a[8], b[4];
#pragma unroll
      for (int j = 0; j < 4; ++j)
        b[j] = *(const bf16x8*)swz(cb + 32768, wc * 64 + j * 16 + lr, c16);
#pragma unroll
      for (int i = 0; i < 8; ++i)
        a[i] = *(const bf16x8*)swz(cb, wr * 128 + i * 16 + lr, c16);
      __builtin_amdgcn_s_setprio(1);
#pragma unroll
      for (int i = 0; i < 8; ++i)
#pragma unroll
        for (int j = 0; j < 4; ++j)
          acc[i][j] = __builtin_amdgcn_mfma_f32_16x16x32_bf16(a[i], b[j], acc[i][j], 0, 0, 0);
      __builtin_amdgcn_s_setprio(0);
    }
    if (pf) stageA_write_bf16(av, nb, tid);
    __syncthreads();
  }

  // epilogue: C/D layout col=lane&15, row=(lane>>4)*4+r  [m89]
#pragma unroll
  for (int i = 0; i < 8; ++i) {
    int m0 = tm + wr * 128 + i * 16 + (lane >> 4) * 4;
#pragma unroll
    for (int j = 0; j < 4; ++j) {
      int n = tn + wc * 64 + j * 16 + (lane & 15);
      float bb = bias[n];
#pragma unroll
      for (int r = 0; r < 4; ++r)
        C[(size_t)(m0 + r) * N + n] = __float2bfloat16(acc[i][j][r] + bb);
    }
  }
}

// ---------------------------------------------------------------- GEMM2: out = x + alpha*(spikes @ w_q8T * scale + b_out)  (R18 body + XCD map)
__global__ __launch_bounds__(512, 1) void gemm2_i8_k(
    const signed char* __restrict__ A, const signed char* __restrict__ BT,
    float* __restrict__ C, const float* __restrict__ qscale,
    const float* __restrict__ bias, const float* __restrict__ xres,
    const float* __restrict__ alpha_p, int M, int N, int K) {
  __shared__ char lds[131072];
  const int tid = threadIdx.x, lane = tid & 63, w = tid >> 6;
  const int wr = w >> 2, wc = w & 3;
  int tm, tn;
  xcd_tile(blockIdx.x, tm, tn);
  const int lr = lane & 15;
  const int lc = lane >> 4;
  const int NT = K >> 7;  // 16

  i32x4 acc[8][4] = {};

  stage_row_i8(A,  K, tm, 0, lds + 0,     tid);
  stage_row_i8(BT, K, tn, 0, lds + 32768, tid);
  __syncthreads();

  for (int t = 0; t < NT; ++t) {
    const char* cb = lds + (t & 1) * 65536;
    char* nb = lds + ((t + 1) & 1) * 65536;
    if (t + 1 < NT) {
      stage_row_i8(A,  K, tm, (t + 1) * 128, nb + 0,     tid);
      stage_row_i8(BT, K, tn, (t + 1) * 128, nb + 32768, tid);
    }
#pragma unroll
    for (int kh = 0; kh < 2; ++kh) {
      const int c16 = lc + kh * 4;
      i32x4 a[8], b[4];
#pragma unroll
      for (int j = 0; j < 4; ++j)
        b[j] = *(const i32x4*)swz(cb + 32768, wc * 64 + j * 16 + lr, c16);
#pragma unroll
      for (int i = 0; i < 8; ++i)
        a[i] = *(const i32x4*)swz(cb, wr * 128 + i * 16 + lr, c16);
      __builtin_amdgcn_s_setprio(1);
#pragma unroll
      for (int i = 0; i < 8; ++i)
#pragma unroll
        for (int j = 0; j < 4; ++j)
          acc[i][j] = __builtin_amdgcn_mfma_i32_16x16x64_i8(a[i], b[j], acc[i][j], 0, 0, 0);
      __builtin_amdgcn_s_setprio(0);
    }
    __syncthreads();
  }

  float alpha = *alpha_p;
#pragma unroll
  for (int i = 0; i < 8; ++i) {
    int m0 = tm + wr * 128 + i * 16 + (lane >> 4) * 4;
#pragma unroll
    for (int j = 0; j < 4; ++j) {
      int n = tn + wc * 64 + j * 16 + (lane & 15);
      float sc = qscale[n];
      float bb = bias[n];
#pragma unroll
      for (int r = 0; r < 4; ++r) {
        size_t idx = (size_t)(m0 + r) * N + n;
        C[idx] = xres[idx] + alpha * ((float)acc[i][j][r] * sc + bb);
      }
    }
  }
}

// ---------------------------------------------------------------- chunked LIF scan (bf16 in, u8 out)
__global__ void snn_scan_k(const bf16* __restrict__ xp, unsigned char* __restrict__ sp,
                           const float* __restrict__ thre_p,
                           int T, int H, int CHUNK, int WARM) {
  int h = blockIdx.x * blockDim.x + threadIdx.x;
  int b = blockIdx.y;
  int c = blockIdx.z;
  float thre = *thre_p;
  float l1 = thre, l2 = 2.f * thre, l3 = 3.f * thre, l4 = 4.f * thre;
  int t0 = c * CHUNK;
  int tw = t0 - WARM;
  if (tw < 0) tw = 0;
  const bf16* xcol = xp + (size_t)b * T * H + h;
  unsigned char* scol = sp + (size_t)b * T * H + h;
  float mem = 0.f;
  for (int t = tw; t < t0; ++t) {  // warmup: state error 0.25^16 ~ 2e-10
    float xv = __bfloat162float(xcol[(size_t)t * H]);
    mem = DECAY * mem + xv;
    int s = (mem >= l1) + (mem >= l2) + (mem >= l3) + (mem >= l4);
    mem -= (float)s * thre;
  }
  for (int t = t0; t < t0 + CHUNK; ++t) {
    float xv = __bfloat162float(xcol[(size_t)t * H]);
    mem = DECAY * mem + xv;
    int s = (mem >= l1) + (mem >= l2) + (mem >= l3) + (mem >= l4);
    mem -= (float)s * thre;
    scol[(size_t)t * H] = (unsigned char)s;
  }
}

// ---------------------------------------------------------------- launch
extern "C" void kernel_launch(void* const* d_in, const int* in_sizes, int n_in,
                              void* d_out, int out_size, void* d_ws, size_t ws_size,
                              hipStream_t stream) {
  const float* x     = (const float*)d_in[0];
  const float* alpha = (const float*)d_in[1];
  const float* thre  = (const float*)d_in[2];
  const float* w_in  = (const float*)d_in[3];
  const float* b_in  = (const float*)d_in[4];
  const float* w_out = (const float*)d_in[5];
  const float* b_out = (const float*)d_in[6];
  float* out = (float*)d_out;

  const int B = 4, T = 2048, H = 2048;
  const int M = B * T;  // 8192
  const int K = H, N = H;
  const int NSLAB = 16;

  char* ws = (char*)d_ws;
  size_t off = 0;
  signed char* spikes = (signed char*)(ws + off); off += (size_t)M * K;      // 16.8MB
  bf16* w_inT   = (bf16*)(ws + off);              off += (size_t)K * N * 2;  // 8.4MB
  signed char* w_q8T = (signed char*)(ws + off);  off += (size_t)K * N;      // 4.2MB
  float* partials = (float*)(ws + off);           off += (size_t)NSLAB * N * 4;
  float* qscale  = (float*)(ws + off);            off += (size_t)N * 4;
  bf16* xp      = (bf16*)(ws + off);              off += (size_t)M * K * 2;  // 33.5MB

  dim3 tb(32, 8);
  dim3 tg(N / 32, K / 32);
  transpose_cast_k<<<tg, tb, 0, stream>>>(w_in, w_inT, N);

  const int KCH = K / NSLAB;  // 128
  dim3 cg(N / 256, NSLAB);
  colmax_part_k<<<cg, 256, 0, stream>>>(w_out, partials, N, KCH);
  transpose_quant_k<<<tg, tb, 0, stream>>>(w_out, partials, w_q8T, qscale, N, K, NSLAB);

  const int NWG = (M / 256) * (N / 256);  // 256 blocks, 1-D grid with XCD mapping
  gemm1_bf16_k<<<NWG, 512, 0, stream>>>(x, w_inT, xp, b_in, M, N, K);

  const int CHUNK = 128, WARM = 16, NC = T / CHUNK;
  dim3 sg(H / 256, B, NC);
  snn_scan_k<<<sg, 256, 0, stream>>>(xp, (unsigned char*)spikes, thre, T, H, CHUNK, WARM);

  gemm2_i8_k<<<NWG, 512, 0, stream>>>(spikes, w_q8T, out, qscale, b_out, x, alpha, M, N, K);
}